// Round 3
// baseline (127.116 us; speedup 1.0000x reference)
//
#include <hip/hip_runtime.h>
#include <cstdint>

// ---------------------------------------------------------------------------
// Composer_81707457839189:
//   Vmin = min(V, axis=0);  Vcorr = max(V - Vmin + e, e)
//   phi  = (1+w)*Vcorr + b
//   G    = triu(gammas,1) + triu(gammas,1)^T
//   P[n,i,j] = phi_i^G * phi_j^(1-G)  (diag = phi_i);  modal = sum_j P
//   logits = log_softmax(-0.25*modal);  alphas = exp(logits)
// Output: d_out = [alphas (N*16) | logits (N*16)] fp32
// ---------------------------------------------------------------------------

#define EC    2.71828182845904523536f
#define LOG2E 1.44269504088896340736f
#define LN2   0.69314718055994530942f

__device__ __forceinline__ unsigned int ordmap(float f) {
    unsigned int u = __float_as_uint(f);
    return u ^ ((unsigned int)((int)u >> 31) | 0x80000000u);
}
__device__ __forceinline__ float ordunmap(unsigned int u) {
    unsigned int bits = (u & 0x80000000u) ? (u ^ 0x80000000u) : ~u;
    return __uint_as_float(bits);
}

// ws[0..15] <- +inf (mapped). ws is re-poisoned to 0xAA before every timed
// launch, so this init must run every kernel_launch call.
__global__ void k_init(unsigned int* __restrict__ ws) {
    if (threadIdx.x < 16) ws[threadIdx.x] = 0xFFFFFFFFu;
}

// Per-column min of V (N x 16, row-major) via ordered-uint atomicMin.
// Flat float4 view: float4 element i, slot k holds column 4*(i%4)+k.
// Grid stride is a multiple of 4, so each thread owns one fixed column group.
__global__ __launch_bounds__(256) void k_colmin(const float4* __restrict__ V4,
                                                unsigned int* __restrict__ ws,
                                                int n4) {
    int tid = blockIdx.x * blockDim.x + threadIdx.x;
    int stride = gridDim.x * blockDim.x;  // multiple of 4
    float4 m = make_float4(__builtin_inff(), __builtin_inff(),
                           __builtin_inff(), __builtin_inff());
    for (int i = tid; i < n4; i += stride) {
        float4 v = V4[i];
        m.x = fminf(m.x, v.x);
        m.y = fminf(m.y, v.y);
        m.z = fminf(m.z, v.z);
        m.w = fminf(m.w, v.w);
    }
    // Fold lanes sharing lane%4 (xor over bits 2..5 of the lane id).
    #pragma unroll
    for (int off = 4; off <= 32; off <<= 1) {
        m.x = fminf(m.x, __shfl_xor(m.x, off));
        m.y = fminf(m.y, __shfl_xor(m.y, off));
        m.z = fminf(m.z, __shfl_xor(m.z, off));
        m.w = fminf(m.w, __shfl_xor(m.w, off));
    }
    __shared__ float lmin[4][16];
    int lane = threadIdx.x & 63;
    int wv   = threadIdx.x >> 6;
    if (lane < 4) {  // lane == column group
        lmin[wv][lane * 4 + 0] = m.x;
        lmin[wv][lane * 4 + 1] = m.y;
        lmin[wv][lane * 4 + 2] = m.z;
        lmin[wv][lane * 4 + 3] = m.w;
    }
    __syncthreads();
    if (threadIdx.x < 16) {
        float mm = fminf(fminf(lmin[0][threadIdx.x], lmin[1][threadIdx.x]),
                         fminf(lmin[2][threadIdx.x], lmin[3][threadIdx.x]));
        atomicMin(&ws[threadIdx.x], ordmap(mm));
    }
}

__global__ __launch_bounds__(256) void k_main(const float* __restrict__ V,
                                              const float* __restrict__ w,
                                              const float* __restrict__ b,
                                              const float* __restrict__ gam,
                                              const unsigned int* __restrict__ wsmin,
                                              float* __restrict__ out, int N) {
    __shared__ float s_cw[16], s_cb[16], s_vmin[16];
    __shared__ float s_g[16][16];
    int t = threadIdx.x;
    if (t < 16) {
        s_cw[t]   = 1.0f + w[t];
        s_cb[t]   = b[t];
        s_vmin[t] = ordunmap(wsmin[t]);
    }
    {   // symmetrize gammas: G[i][j] = gammas[min(i,j)][max(i,j)], diag unused
        int i = t >> 4, j = t & 15;
        s_g[i][j] = (i < j) ? gam[i * 16 + j] : ((i > j) ? gam[j * 16 + i] : 0.0f);
    }
    __syncthreads();

    int r = blockIdx.x * blockDim.x + t;
    if (r >= N) return;

    const float4* Vr = (const float4*)(V + (size_t)r * 16);
    float4 v0 = Vr[0], v1 = Vr[1], v2 = Vr[2], v3 = Vr[3];
    float vf[16] = {v0.x, v0.y, v0.z, v0.w, v1.x, v1.y, v1.z, v1.w,
                    v2.x, v2.y, v2.z, v2.w, v3.x, v3.y, v3.z, v3.w};

    float phi[16], L[16], modal[16];
    #pragma unroll
    for (int i = 0; i < 16; ++i) {
        float vc = fmaxf(vf[i] - s_vmin[i] + EC, EC);
        float p  = __builtin_fmaf(s_cw[i], vc, s_cb[i]);
        phi[i]   = p;
        L[i]     = __builtin_amdgcn_logf(p);   // v_log_f32 (log2)
        modal[i] = p;                           // diagonal term
    }

    // P[i,j] = exp2(L[j] + g*d), P[j,i] = exp2(L[i] - g*d), d = L[i]-L[j]
    #pragma unroll
    for (int i = 0; i < 16; ++i) {
        #pragma unroll
        for (int j = i + 1; j < 16; ++j) {
            float d = L[i] - L[j];
            float g = s_g[i][j];              // wave-uniform LDS broadcast
            modal[i] += __builtin_amdgcn_exp2f(__builtin_fmaf(g,  d, L[j]));
            modal[j] += __builtin_amdgcn_exp2f(__builtin_fmaf(-g, d, L[i]));
        }
    }

    // log-softmax of x = -0.25 * modal
    float x[16];
    float mx = -__builtin_inff();
    #pragma unroll
    for (int i = 0; i < 16; ++i) {
        x[i] = -0.25f * modal[i];
        mx   = fmaxf(mx, x[i]);
    }
    float e[16], s = 0.0f;
    #pragma unroll
    for (int i = 0; i < 16; ++i) {
        e[i] = __builtin_amdgcn_exp2f((x[i] - mx) * LOG2E);
        s += e[i];
    }
    float inv = 1.0f / s;
    float lns = __builtin_amdgcn_logf(s) * LN2;  // log2(s)*ln2 = ln(s)

    float a[16], l[16];
    #pragma unroll
    for (int i = 0; i < 16; ++i) {
        a[i] = e[i] * inv;
        l[i] = x[i] - mx - lns;
    }

    float4* oa = (float4*)(out + (size_t)r * 16);
    float4* ol = (float4*)(out + (size_t)N * 16 + (size_t)r * 16);
    oa[0] = make_float4(a[0],  a[1],  a[2],  a[3]);
    oa[1] = make_float4(a[4],  a[5],  a[6],  a[7]);
    oa[2] = make_float4(a[8],  a[9],  a[10], a[11]);
    oa[3] = make_float4(a[12], a[13], a[14], a[15]);
    ol[0] = make_float4(l[0],  l[1],  l[2],  l[3]);
    ol[1] = make_float4(l[4],  l[5],  l[6],  l[7]);
    ol[2] = make_float4(l[8],  l[9],  l[10], l[11]);
    ol[3] = make_float4(l[12], l[13], l[14], l[15]);
}

extern "C" void kernel_launch(void* const* d_in, const int* in_sizes, int n_in,
                              void* d_out, int out_size, void* d_ws, size_t ws_size,
                              hipStream_t stream) {
    (void)n_in; (void)out_size; (void)ws_size;
    const float* V   = (const float*)d_in[0];
    const float* w   = (const float*)d_in[1];
    const float* b   = (const float*)d_in[2];
    const float* gam = (const float*)d_in[3];
    float* out = (float*)d_out;
    unsigned int* wsmin = (unsigned int*)d_ws;

    const int N  = in_sizes[0] / 16;
    const int n4 = N * 4;  // float4 count

    hipLaunchKernelGGL(k_init, dim3(1), dim3(64), 0, stream, wsmin);
    hipLaunchKernelGGL(k_colmin, dim3(1024), dim3(256), 0, stream,
                       (const float4*)V, wsmin, n4);
    hipLaunchKernelGGL(k_main, dim3((N + 255) / 256), dim3(256), 0, stream,
                       V, w, b, gam, wsmin, out, N);
}